// Round 5
// baseline (97.737 us; speedup 1.0000x reference)
//
#include <hip/hip_runtime.h>

typedef float f32x4 __attribute__((ext_vector_type(4)));
typedef short s16x8 __attribute__((ext_vector_type(8)));
typedef unsigned short u16x8 __attribute__((ext_vector_type(8)));
typedef unsigned int u32;

// ---------- helpers ----------
__device__ __forceinline__ unsigned short f2bf(float f) {
  u32 x = __float_as_uint(f);
  u32 r = (x + 0x7fffu + ((x >> 16) & 1u)) >> 16;  // RNE
  return (unsigned short)r;
}

__device__ __forceinline__ void gload16(const void* g, void* lds) {
  __builtin_amdgcn_global_load_lds(
      (const __attribute__((address_space(1))) u32*)(uintptr_t)g,
      (__attribute__((address_space(3))) u32*)(u32)(uintptr_t)lds,
      16, 0, 0);
}

// ============================================================================
// A staged as 16 KiB "units" = one (256-row x 32-k) k-half of a 256x64 K-tile,
// stored as the exact LDS image: byte o = r*64 + c_lds*16, chunk at (r,c_lds)
// holds k-chunk kq = c_lds ^ ((r>>1)&3) (conflict-free ds_read_b128; dest of
// global_load_lds linear, source pre-swizzled). Unit idx: (bm*16+ks)*2+kh.
// B identical with packed-n rows: n = (j>>4)<<6 | gate<<4 | (j&15) -> a
// wave's 4 n-frags = the 4 gates of one j => lane-local LSTM epilogue.
// ============================================================================

__global__ __launch_bounds__(256) void pack_a_kernel(const float* __restrict__ X,
                                                     const float* __restrict__ C,
                                                     unsigned short* __restrict__ At) {
  int idx = blockIdx.x * 256 + threadIdx.x;  // 2,097,152 chunks of 16B
  int u = idx >> 10;
  int co = idx & 1023;
  int r = co >> 2, cl = co & 3;
  int bm = u >> 5, ks = (u >> 1) & 15, kh = u & 1;
  int row = bm * 256 + r;
  int kq = cl ^ ((r >> 1) & 3);
  int k = ks * 64 + kh * 32 + kq * 8;
  const float* src = (k < 512) ? (X + (size_t)row * 512 + k)
                               : (C + (size_t)row * 512 + (k - 512));
  float4 v0 = *(const float4*)src;
  float4 v1 = *(const float4*)(src + 4);
  u16x8 h;
  h[0] = f2bf(v0.x); h[1] = f2bf(v0.y); h[2] = f2bf(v0.z); h[3] = f2bf(v0.w);
  h[4] = f2bf(v1.x); h[5] = f2bf(v1.y); h[6] = f2bf(v1.z); h[7] = f2bf(v1.w);
  *(u16x8*)((char*)At + (size_t)idx * 16) = h;
}

__global__ __launch_bounds__(256) void pack_b_kernel(
    const float* __restrict__ Wf, const float* __restrict__ Wi,
    const float* __restrict__ Wo, const float* __restrict__ Wc,
    const float* __restrict__ Uf, const float* __restrict__ Ui,
    const float* __restrict__ Uo, const float* __restrict__ Uc,
    unsigned short* __restrict__ Bt) {
  int idx = blockIdx.x * 256 + threadIdx.x;  // 262,144 chunks
  int u = idx >> 10;
  int co = idx & 1023;
  int r = co >> 2, cl = co & 3;
  int bn = u >> 5, ks = (u >> 1) & 15, kh = u & 1;
  int n = bn * 256 + r;
  int g = (n >> 4) & 3;
  int j = ((n >> 6) << 4) | (n & 15);
  int kq = cl ^ ((r >> 1) & 3);
  int k = ks * 64 + kh * 32 + kq * 8;
  const float* Wg = (g == 0) ? Wf : (g == 1) ? Wi : (g == 2) ? Wo : Wc;
  const float* Ug = (g == 0) ? Uf : (g == 1) ? Ui : (g == 2) ? Uo : Uc;
  const float* M = (k < 512) ? (Wg + (size_t)k * 512) : (Ug + (size_t)(k - 512) * 512);
  u16x8 h;
#pragma unroll
  for (int e = 0; e < 8; ++e) h[e] = f2bf(M[(size_t)e * 512 + j]);
  *(u16x8*)((char*)Bt + (size_t)idx * 16) = h;
}

// ============================================================================
// 256x256x(BK=64) 8-phase GEMM, READ-AHEAD-BY-ONE pipeline.
// LDS: A 4 slots (parity x khalf) x 16 KiB at 0; B same at 65536. 128 KiB.
// Phase P: {stage, [vmcnt(6)], BAR, ds_reads for P+1 (ping-pong regs),
// MFMA(P) on regs loaded at P-1, sched_barrier(0), BAR}. MFMA never depends
// on same-phase reads -> compiler emits COUNTED lgkm waits; read latency
// hides under the ~600-cyc MFMA cluster (round-4 failure: same-phase dep
// serialized LDS drain and MFMA, 25% MfmaUtil).
// Residency: reads at P occur after P's opening BAR; every consumed slot was
// vmcnt-retired at a wait <= P-1 and published by that phase's barrier
// (table re-checked for reads-one-early). Slot-overwrite safety: a slot's
// last read is issued at phase P and completes before MFMA(P+1) (compiler
// wait), which sched_barrier pins before P+1's closing BAR; restage of that
// slot issues >= P+2. No lgkmcnt(0) needed.
// ============================================================================

#define BAR    asm volatile("s_barrier" ::: "memory")
#define WAITV8 asm volatile("s_waitcnt vmcnt(8)" ::: "memory")
#define WAITV6 asm volatile("s_waitcnt vmcnt(6)" ::: "memory")

#define STAGE_A(KS, KH, PDST)                                              \
  do { const char* s_ = gA + (((KS) * 2 + (KH)) << 14) + tid * 16;         \
       char* d_ = lds + (((PDST) * 2 + (KH)) << 14) + tid * 16;            \
       gload16(s_, d_); gload16(s_ + 8192, d_ + 8192); } while (0)
#define STAGE_B(KS, KH, PDST)                                              \
  do { const char* s_ = gB + (((KS) * 2 + (KH)) << 14) + tid * 16;         \
       char* d_ = lds + 65536 + (((PDST) * 2 + (KH)) << 14) + tid * 16;    \
       gload16(s_, d_); gload16(s_ + 8192, d_ + 8192); } while (0)

// load the 4 A-frags of (PAR,KH, m-half MH) into register set S0..S3
#define LDA4(S, PAR, KH, MH)                                                   \
  do { const char* p_ = lds + (((PAR) * 2 + (KH)) << 14) + wr * 8192 +         \
                        (MH) * 4096 + lsw;                                     \
       S##0 = *(const s16x8*)(p_);                                             \
       S##1 = *(const s16x8*)(p_ + 1024);                                      \
       S##2 = *(const s16x8*)(p_ + 2048);                                      \
       S##3 = *(const s16x8*)(p_ + 3072); } while (0)
// load the 4 B-frags of (PAR,KH) into register set S0..S3
#define LDB4(S, PAR, KH)                                                       \
  do { const char* p_ = lds + 65536 + (((PAR) * 2 + (KH)) << 14) +             \
                        wc * 4096 + lsw;                                       \
       S##0 = *(const s16x8*)(p_);                                             \
       S##1 = *(const s16x8*)(p_ + 1024);                                      \
       S##2 = *(const s16x8*)(p_ + 2048);                                      \
       S##3 = *(const s16x8*)(p_ + 3072); } while (0)

#define MFMA16(M0, A, B)                                                                      \
  do {                                                                                        \
    acc[(M0)+0][0] = __builtin_amdgcn_mfma_f32_16x16x32_bf16(A##0, B##0, acc[(M0)+0][0],0,0,0); \
    acc[(M0)+1][0] = __builtin_amdgcn_mfma_f32_16x16x32_bf16(A##1, B##0, acc[(M0)+1][0],0,0,0); \
    acc[(M0)+2][0] = __builtin_amdgcn_mfma_f32_16x16x32_bf16(A##2, B##0, acc[(M0)+2][0],0,0,0); \
    acc[(M0)+3][0] = __builtin_amdgcn_mfma_f32_16x16x32_bf16(A##3, B##0, acc[(M0)+3][0],0,0,0); \
    acc[(M0)+0][1] = __builtin_amdgcn_mfma_f32_16x16x32_bf16(A##0, B##1, acc[(M0)+0][1],0,0,0); \
    acc[(M0)+1][1] = __builtin_amdgcn_mfma_f32_16x16x32_bf16(A##1, B##1, acc[(M0)+1][1],0,0,0); \
    acc[(M0)+2][1] = __builtin_amdgcn_mfma_f32_16x16x32_bf16(A##2, B##1, acc[(M0)+2][1],0,0,0); \
    acc[(M0)+3][1] = __builtin_amdgcn_mfma_f32_16x16x32_bf16(A##3, B##1, acc[(M0)+3][1],0,0,0); \
    acc[(M0)+0][2] = __builtin_amdgcn_mfma_f32_16x16x32_bf16(A##0, B##2, acc[(M0)+0][2],0,0,0); \
    acc[(M0)+1][2] = __builtin_amdgcn_mfma_f32_16x16x32_bf16(A##1, B##2, acc[(M0)+1][2],0,0,0); \
    acc[(M0)+2][2] = __builtin_amdgcn_mfma_f32_16x16x32_bf16(A##2, B##2, acc[(M0)+2][2],0,0,0); \
    acc[(M0)+3][2] = __builtin_amdgcn_mfma_f32_16x16x32_bf16(A##3, B##2, acc[(M0)+3][2],0,0,0); \
    acc[(M0)+0][3] = __builtin_amdgcn_mfma_f32_16x16x32_bf16(A##0, B##3, acc[(M0)+0][3],0,0,0); \
    acc[(M0)+1][3] = __builtin_amdgcn_mfma_f32_16x16x32_bf16(A##1, B##3, acc[(M0)+1][3],0,0,0); \
    acc[(M0)+2][3] = __builtin_amdgcn_mfma_f32_16x16x32_bf16(A##2, B##3, acc[(M0)+2][3],0,0,0); \
    acc[(M0)+3][3] = __builtin_amdgcn_mfma_f32_16x16x32_bf16(A##3, B##3, acc[(M0)+3][3],0,0,0); \
  } while (0)

// One pipeline phase. LOADS = ds_reads for the NEXT phase (disjoint reg set).
#define PHASE(STAGE, WAITSTMT, LOADS, M0, A, B)                                \
  do {                                                                         \
    STAGE;                                                                     \
    WAITSTMT;                                                                  \
    BAR;                                                                       \
    LOADS;                                                                     \
    __builtin_amdgcn_s_setprio(1);                                             \
    MFMA16(M0, A, B);                                                          \
    __builtin_amdgcn_s_setprio(0);                                             \
    __builtin_amdgcn_sched_barrier(0);                                         \
    BAR;                                                                       \
  } while (0)

__global__ __launch_bounds__(512, 2) void gemm_fused(
    const unsigned short* __restrict__ At_, const unsigned short* __restrict__ Bt_,
    const float* __restrict__ c_prev,
    const float* __restrict__ bf_, const float* __restrict__ bi_,
    const float* __restrict__ bo_, const float* __restrict__ bc_,
    float* __restrict__ H) {
  __shared__ __attribute__((aligned(128))) char lds[131072];
  int bid = blockIdx.x;
  int wg = (bid & 7) * 64 + (bid >> 3);  // XCD swizzle, 512 % 8 == 0 -> bijective
  int bn = wg & 7, bm = wg >> 3;
  int tid = threadIdx.x;
  int lane = tid & 63, w = tid >> 6;
  int wr = w >> 2, wc = w & 3;           // 2 x 4 waves
  int l15 = lane & 15, kq = lane >> 4;
  int lsw = l15 * 64 + ((kq ^ ((l15 >> 1) & 3)) << 4);  // per-lane swizzled offset

  const char* gA = (const char*)At_ + (size_t)bm * (32 * 16384);
  const char* gB = (const char*)Bt_ + (size_t)bn * (32 * 16384);

  f32x4 acc[8][4] = {};
  s16x8 ap0, ap1, ap2, ap3, aq0, aq1, aq2, aq3;  // A ping/pong
  s16x8 bp0, bp1, bp2, bp3, bq0, bq1, bq2, bq3;  // B ping/pong

  // prologue: stage tile0 (both k-halves, A+B) + tile1 k-half0 (A+B) = 6 units
  STAGE_A(0, 0, 0); STAGE_B(0, 0, 0);
  STAGE_A(0, 1, 0); STAGE_B(0, 1, 0);
  STAGE_A(1, 0, 1); STAGE_B(1, 0, 1);
  WAITV8;  // 12 issued, <=8 outstanding -> tile0 kh0 (A+B) resident
  BAR;
  // pre-load phase-0 fragments
  LDA4(ap, 0, 0, 0);
  LDB4(bp, 0, 0);

  for (int t = 0; t < 16; t += 2) {
    int p1 = (t + 1) & 15, p2 = (t + 2) & 15, p3 = (t + 3) & 15;
    // tile t (parity 0)
    PHASE(STAGE_A(p1, 1, 1), ,       LDA4(aq, 0, 0, 1),                    0, ap, bp);
    PHASE(STAGE_B(p1, 1, 1), WAITV6, LDA4(ap, 0, 1, 0); LDB4(bq, 0, 1),   4, aq, bp);
    PHASE(STAGE_A(p2, 0, 0), ,       LDA4(aq, 0, 1, 1),                    0, ap, bq);
    PHASE(STAGE_B(p2, 0, 0), WAITV6, LDA4(ap, 1, 0, 0); LDB4(bp, 1, 0),   4, aq, bq);
    // tile t+1 (parity 1)
    PHASE(STAGE_A(p2, 1, 0), ,       LDA4(aq, 1, 0, 1),                    0, ap, bp);
    PHASE(STAGE_B(p2, 1, 0), WAITV6, LDA4(ap, 1, 1, 0); LDB4(bq, 1, 1),   4, aq, bp);
    PHASE(STAGE_A(p3, 0, 1), ,       LDA4(aq, 1, 1, 1),                    0, ap, bq);
    PHASE(STAGE_B(p3, 0, 1), WAITV6, LDA4(ap, 0, 0, 0); LDB4(bp, 0, 0),   4, aq, bq);
  }

  // ---------------- epilogue: lane-local LSTM gates ----------------
  int j = (bn * 4 + wc) * 16 + l15;
  float vbf = bf_[j], vbi = bi_[j], vbo = bo_[j], vbc = bc_[j];
  int row0 = bm * 256 + wr * 128 + kq * 4;
#pragma unroll
  for (int m = 0; m < 8; ++m) {
#pragma unroll
    for (int ri = 0; ri < 4; ++ri) {
      int row = row0 + m * 16 + ri;
      float fp = acc[m][0][ri] + vbf;
      float ip = acc[m][1][ri] + vbi;
      float op = acc[m][2][ri] + vbo;
      float cq = acc[m][3][ri] + vbc;
      float ft = 1.0f / (1.0f + __expf(-fp));
      float it = 1.0f / (1.0f + __expf(-ip));
      float ot = 1.0f / (1.0f + __expf(-op));
      float ch = 1.0f - 2.0f / (1.0f + __expf(2.0f * cq));
      float cp = c_prev[(size_t)row * 512 + j];
      float ct = ft * cp + it * ch;
      float th = 1.0f - 2.0f / (1.0f + __expf(2.0f * ct));
      H[(size_t)row * 512 + j] = ot * th;
    }
  }
}

extern "C" void kernel_launch(void* const* d_in, const int* in_sizes, int n_in,
                              void* d_out, int out_size, void* d_ws, size_t ws_size,
                              hipStream_t stream) {
  const float* X = (const float*)d_in[0];
  const float* Cp = (const float*)d_in[1];
  const float* Wf = (const float*)d_in[2];
  const float* Wi = (const float*)d_in[3];
  const float* Wo = (const float*)d_in[4];
  const float* Wc = (const float*)d_in[5];
  const float* Uf = (const float*)d_in[6];
  const float* Ui = (const float*)d_in[7];
  const float* Uo = (const float*)d_in[8];
  const float* Uc = (const float*)d_in[9];
  const float* bfp = (const float*)d_in[10];
  const float* bip = (const float*)d_in[11];
  const float* bop = (const float*)d_in[12];
  const float* bcp = (const float*)d_in[13];
  float* H = (float*)d_out;

  unsigned short* At = (unsigned short*)d_ws;                       // 32 MiB
  unsigned short* Bt = (unsigned short*)((char*)d_ws + 33554432u);  //  4 MiB

  pack_a_kernel<<<8192, 256, 0, stream>>>(X, Cp, At);
  pack_b_kernel<<<1024, 256, 0, stream>>>(Wf, Wi, Wo, Wc, Uf, Ui, Uo, Uc, Bt);
  gemm_fused<<<512, 512, 0, stream>>>(At, Bt, Cp, bfp, bip, bop, bcp, H);
}

// Round 6
// 93.253 us; speedup vs baseline: 1.0481x; 1.0481x over previous
//
#include <hip/hip_runtime.h>

typedef float f32x4 __attribute__((ext_vector_type(4)));
typedef short s16x8 __attribute__((ext_vector_type(8)));
typedef unsigned short u16x8 __attribute__((ext_vector_type(8)));
typedef unsigned int u32;

// ---------- helpers ----------
__device__ __forceinline__ unsigned short f2bf(float f) {
  u32 x = __float_as_uint(f);
  u32 r = (x + 0x7fffu + ((x >> 16) & 1u)) >> 16;  // RNE
  return (unsigned short)r;
}

__device__ __forceinline__ void gload16(const void* g, void* lds) {
  // global -> LDS direct copy, 16B per lane, LDS dest = wave-uniform base + lane*16
  __builtin_amdgcn_global_load_lds(
      (const __attribute__((address_space(1))) u32*)(uintptr_t)g,
      (__attribute__((address_space(3))) u32*)(u32)(uintptr_t)lds,
      16, 0, 0);
}

// ---------- pack A: [X | c_prev] -> bf16, tiled (128 rows x 64 k), chunk-swizzled ----------
// A_t tile (RB, KS) at byte offset (RB*16+KS)*16384; element (r, k') at
// r*128 + ((chunk ^ (r&7))<<4) + (k'%8)*2, chunk = k'/8.
__global__ __launch_bounds__(256) void pack_a_kernel(const float* __restrict__ X,
                                                     const float* __restrict__ C,
                                                     unsigned short* __restrict__ At) {
  int idx = blockIdx.x * 256 + threadIdx.x;  // one thread per 16B chunk; 2,097,152 total
  int row = idx >> 7;
  int kc = idx & 127;  // global k-chunk 0..127 (k = kc*8)
  const float* src = (kc < 64) ? (X + row * 512 + kc * 8)
                               : (C + row * 512 + (kc - 64) * 8);
  float4 v0 = *(const float4*)src;
  float4 v1 = *(const float4*)(src + 4);
  u16x8 h;
  h[0] = f2bf(v0.x); h[1] = f2bf(v0.y); h[2] = f2bf(v0.z); h[3] = f2bf(v0.w);
  h[4] = f2bf(v1.x); h[5] = f2bf(v1.y); h[6] = f2bf(v1.z); h[7] = f2bf(v1.w);
  int tile = ((row >> 7) << 4) + (kc >> 3);
  int r = row & 127, c = kc & 7;
  char* dst = (char*)At + (size_t)tile * 16384 + r * 128 + ((c ^ (r & 7)) << 4);
  *(u16x8*)dst = h;
}

// ---------- pack B: W/U columns -> B_t[n][k] bf16, gate-interleaved, tiled+swizzled ----------
// n = (j/16)*64 + g*16 + (j%16); B_t tile (NB, KS) at (NB*16+KS)*16384, same swizzle as A.
__global__ __launch_bounds__(256) void pack_b_kernel(
    const float* __restrict__ Wf, const float* __restrict__ Wi,
    const float* __restrict__ Wo, const float* __restrict__ Wc,
    const float* __restrict__ Uf, const float* __restrict__ Ui,
    const float* __restrict__ Uo, const float* __restrict__ Uc,
    unsigned short* __restrict__ Bt) {
  __shared__ float T[64][68];  // 64k x 64j tile, padded
  int bid = blockIdx.x;        // 512 blocks: 4 gates x 8 j-tiles x 16 k-tiles
  int kt = bid & 15;
  int jt = (bid >> 4) & 7;
  int g = bid >> 7;
  const float* Wg = (g == 0) ? Wf : (g == 1) ? Wi : (g == 2) ? Wo : Wc;
  const float* Ug = (g == 0) ? Uf : (g == 1) ? Ui : (g == 2) ? Uo : Uc;
  const float* srcbase = (kt < 8) ? (Wg + (size_t)kt * 64 * 512)
                                  : (Ug + (size_t)(kt - 8) * 64 * 512);
  int j0 = jt * 64;
  int tid = threadIdx.x;
  int kk = tid >> 2, q = tid & 3;  // 4 threads per k-row, 16 floats each
  const float* rp = srcbase + (size_t)kk * 512 + j0 + q * 16;
  float4 a = *(const float4*)(rp);
  float4 b = *(const float4*)(rp + 4);
  float4 c4 = *(const float4*)(rp + 8);
  float4 d = *(const float4*)(rp + 12);
  *(float4*)&T[kk][q * 16] = a;
  *(float4*)&T[kk][q * 16 + 4] = b;
  *(float4*)&T[kk][q * 16 + 8] = c4;
  *(float4*)&T[kk][q * 16 + 12] = d;
  __syncthreads();
  for (int ci = tid; ci < 512; ci += 256) {  // 64 j x 8 chunks
    int jj = ci >> 3, c = ci & 7;
    u16x8 h;
#pragma unroll
    for (int e = 0; e < 8; ++e) h[e] = f2bf(T[c * 8 + e][jj]);
    int j = j0 + jj;
    int n = ((j >> 4) << 6) + (g << 4) + (j & 15);
    int NB = n >> 7, r = n & 127;
    char* dst = (char*)Bt + (size_t)(NB * 16 + kt) * 16384 + r * 128 +
                ((c ^ (r & 7)) << 4);
    *(u16x8*)dst = h;
  }
}

// ---------- fused GEMM + LSTM epilogue (128x128 tile, m97 skeleton) ----------
// C_pre[16384][2048] = A(16384x1024) @ B^T(2048x1024); packed col n: gate=(n>>4)&3,
// j=(n>>6)*16+(n&15). Each wave owns 64 rows x 64 packed cols = 16 j's; its 4 n-frags
// are exactly gates f,i,o,c for the same j at the same lane -> lane-local epilogue.
// __launch_bounds__(256,4): force total regs <=128 -> 4 waves/SIMD -> 4 blocks/CU
// (round-1 measured 3 blocks/CU, register-capped; LDS 32KiB allows 5).
// Inner loop restructured kk-outer / B-per-kk / A-per-m to cut live operand
// registers from 64 to ~20 so the 128-reg budget holds without spills.
__global__ __launch_bounds__(256, 4) void gemm_fused(
    const unsigned short* __restrict__ At, const unsigned short* __restrict__ Bt,
    const float* __restrict__ c_prev,
    const float* __restrict__ bf_, const float* __restrict__ bi_,
    const float* __restrict__ bo_, const float* __restrict__ bc_,
    float* __restrict__ H) {
  __shared__ __align__(16) char As[16384];
  __shared__ __align__(16) char Bs[16384];
  int bid = blockIdx.x;
  int wg = (bid & 7) * 256 + (bid >> 3);  // XCD-aware swizzle (2048 % 8 == 0)
  int bn = wg & 15, bm = wg >> 4;
  int tid = threadIdx.x;
  int lane = tid & 63, w = tid >> 6;
  int wr = w >> 1, wc = w & 1;
  int l15 = lane & 15, kq = lane >> 4;

  const char* gA = (const char*)At + (size_t)bm * (16 * 16384) + w * 4096 + lane * 16;
  const char* gB = (const char*)Bt + (size_t)bn * (16 * 16384) + w * 4096 + lane * 16;

  f32x4 acc[4][4] = {};

  int aoff[4][2], boff[4][2];
#pragma unroll
  for (int m = 0; m < 4; ++m) {
    int r = wr * 64 + m * 16 + l15;
    aoff[m][0] = r * 128 + (((kq) ^ (r & 7)) << 4);
    aoff[m][1] = r * 128 + (((kq + 4) ^ (r & 7)) << 4);
  }
#pragma unroll
  for (int n = 0; n < 4; ++n) {
    int r = wc * 64 + n * 16 + l15;
    boff[n][0] = r * 128 + (((kq) ^ (r & 7)) << 4);
    boff[n][1] = r * 128 + (((kq + 4) ^ (r & 7)) << 4);
  }

  for (int ks = 0; ks < 16; ++ks) {
    __syncthreads();
#pragma unroll
    for (int i = 0; i < 4; ++i) {
      gload16(gA + ks * 16384 + i * 1024, As + w * 4096 + i * 1024);
      gload16(gB + ks * 16384 + i * 1024, Bs + w * 4096 + i * 1024);
    }
    __syncthreads();
#pragma unroll
    for (int kk = 0; kk < 2; ++kk) {
      s16x8 b0 = *(const s16x8*)(Bs + boff[0][kk]);
      s16x8 b1 = *(const s16x8*)(Bs + boff[1][kk]);
      s16x8 b2 = *(const s16x8*)(Bs + boff[2][kk]);
      s16x8 b3 = *(const s16x8*)(Bs + boff[3][kk]);
#pragma unroll
      for (int m = 0; m < 4; ++m) {
        s16x8 am = *(const s16x8*)(As + aoff[m][kk]);
        acc[m][0] = __builtin_amdgcn_mfma_f32_16x16x32_bf16(am, b0, acc[m][0], 0, 0, 0);
        acc[m][1] = __builtin_amdgcn_mfma_f32_16x16x32_bf16(am, b1, acc[m][1], 0, 0, 0);
        acc[m][2] = __builtin_amdgcn_mfma_f32_16x16x32_bf16(am, b2, acc[m][2], 0, 0, 0);
        acc[m][3] = __builtin_amdgcn_mfma_f32_16x16x32_bf16(am, b3, acc[m][3], 0, 0, 0);
      }
    }
  }

  // epilogue: acc[m][g] = pre-activation of gate g for (row, j), lane-local
  int jgroup = 2 * bn + wc;
  int j = jgroup * 16 + l15;
  float vbf = bf_[j], vbi = bi_[j], vbo = bo_[j], vbc = bc_[j];
  int row0 = bm * 128 + wr * 64 + kq * 4;
#pragma unroll
  for (int m = 0; m < 4; ++m) {
#pragma unroll
    for (int ri = 0; ri < 4; ++ri) {
      int row = row0 + m * 16 + ri;
      float fp = acc[m][0][ri] + vbf;
      float ip = acc[m][1][ri] + vbi;
      float op = acc[m][2][ri] + vbo;
      float cq = acc[m][3][ri] + vbc;
      float ft = 1.0f / (1.0f + __expf(-fp));
      float it = 1.0f / (1.0f + __expf(-ip));
      float ot = 1.0f / (1.0f + __expf(-op));
      float ch = 1.0f - 2.0f / (1.0f + __expf(2.0f * cq));
      float cp = c_prev[(size_t)row * 512 + j];
      float ct = ft * cp + it * ch;
      float th = 1.0f - 2.0f / (1.0f + __expf(2.0f * ct));
      H[(size_t)row * 512 + j] = ot * th;
    }
  }
}

extern "C" void kernel_launch(void* const* d_in, const int* in_sizes, int n_in,
                              void* d_out, int out_size, void* d_ws, size_t ws_size,
                              hipStream_t stream) {
  const float* X = (const float*)d_in[0];
  const float* Cp = (const float*)d_in[1];
  const float* Wf = (const float*)d_in[2];
  const float* Wi = (const float*)d_in[3];
  const float* Wo = (const float*)d_in[4];
  const float* Wc = (const float*)d_in[5];
  const float* Uf = (const float*)d_in[6];
  const float* Ui = (const float*)d_in[7];
  const float* Uo = (const float*)d_in[8];
  const float* Uc = (const float*)d_in[9];
  const float* bfp = (const float*)d_in[10];
  const float* bip = (const float*)d_in[11];
  const float* bop = (const float*)d_in[12];
  const float* bcp = (const float*)d_in[13];
  float* H = (float*)d_out;

  unsigned short* At = (unsigned short*)d_ws;                       // 33,554,432 B
  unsigned short* Bt = (unsigned short*)((char*)d_ws + 33554432u);  //  4,194,304 B

  pack_a_kernel<<<8192, 256, 0, stream>>>(X, Cp, At);
  pack_b_kernel<<<512, 256, 0, stream>>>(Wf, Wi, Wo, Wc, Uf, Ui, Uo, Uc, Bt);
  gemm_fused<<<2048, 256, 0, stream>>>(At, Bt, Cp, bfp, bip, bop, bcp, H);
}